// Round 1
// baseline (3428.002 us; speedup 1.0000x reference)
//
#include <hip/hip_runtime.h>
#include <hip/hip_fp16.h>

// Problem: B=256,S=256,T=32,H=512,E=128,V=1000,A=8,NT=80.
// Key math fact: scores = enc_score + h@Wd + bf adds a per-column constant over
// the softmax axis (S) -> softmax weights are decoder-independent -> the whole
// decoder is dead code; outputs are pa/pt tiled over T.
//
// Remaining work: 256 sequential LSTM steps (M=256,N=2048,K=640 GEMM each) +
// one attention readout. Structure: persistent kernel, 16 batch-groups x
// (16 rows, 16 wgs), weights in registers (bf16), activations split hi/lo bf16
// (2 MFMAs, ~fp32-accurate), per-group atomic barrier once per step.

#define Bv 256
#define Sv 256
#define Tv 32
#define Hv 512
#define Ev 128
#define KT 20          // k-tiles of 32 over K=640 (4 x-tiles + 16 h-tiles)
#define LDSA 648       // padded k-stride for LDS A planes (shorts): 648%... row stride 1296B -> 2-way bank alias only (free)
#define GM 16          // batch rows per group
#define WPG 16         // workgroups per group

typedef __attribute__((ext_vector_type(8))) short bf16x8;
typedef __attribute__((ext_vector_type(4))) short short4v;
typedef __attribute__((ext_vector_type(4))) float f32x4;

__device__ __forceinline__ unsigned short f2bf(float x) {   // RNE fp32->bf16
  unsigned u = __builtin_bit_cast(unsigned, x);
  u += 0x7fffu + ((u >> 16) & 1u);
  return (unsigned short)(u >> 16);
}
__device__ __forceinline__ float bf2f(unsigned short h) {
  unsigned u = ((unsigned)h) << 16;
  return __builtin_bit_cast(float, u);
}
__device__ __forceinline__ float sigm(float x) { return 1.0f / (1.0f + __expf(-x)); }
__device__ __forceinline__ float tanh_fast(float x) {
  x = fminf(15.f, fmaxf(-15.f, x));
  float e = __expf(2.f * x);
  return (e - 1.f) / (e + 1.f);
}

// hbuf layout: per group g, parity p: [16 rows][512 cols] of packed (bf16_hi | bf16_lo<<16)
// cnt: one counter per group at 64B stride (avoid same-cacheline contention).
__global__ __launch_bounds__(256, 2)
void lstm_enc(const int* __restrict__ enc_in, const float* __restrict__ embed,
              const float* __restrict__ Wi, const float* __restrict__ Wh,
              const float* __restrict__ be,
              unsigned* __restrict__ cnt, unsigned* __restrict__ hbuf,
              __half* __restrict__ enc_out)
{
  __shared__ __attribute__((aligned(16))) short Ahi[GM][LDSA];
  __shared__ __attribute__((aligned(16))) short Alo[GM][LDSA];
  __shared__ float zbuf[4][GM][36];
  __shared__ float cbuf[GM][32];
  __shared__ float biasLDS[128];

  const int tid  = threadIdx.x;
  const int wg   = blockIdx.x;
  const int g    = wg & 15;   // group; wgs of a group share blockIdx%8 -> same XCD (heuristic only)
  const int cb   = wg >> 4;   // column block: owns j in [cb*32, cb*32+32)
  const int wave = tid >> 6;  // wave == gate q (0=i,1=f,2=g,3=o)
  const int lane = tid & 63;
  const int m16  = lane & 15;
  const int qd   = lane >> 4;

  if (tid < 128) biasLDS[tid] = be[(tid >> 5) * 512 + cb * 32 + (tid & 31)];
  cbuf[tid >> 5][tid & 31] = 0.f;
  { int e2 = tid + 256; cbuf[e2 >> 5][e2 & 31] = 0.f; }

  // ---- W fragments in registers: B-operand layout B[k][n]: lane holds
  // W'[n = base + (lane&15)][k = kt*32 + (lane>>4)*8 + j], j=0..7, single bf16.
  bf16x8 wf[KT][2];
#pragma unroll
  for (int kt = 0; kt < KT; ++kt) {
#pragma unroll
    for (int nt = 0; nt < 2; ++nt) {
      int n  = wave * 512 + cb * 32 + nt * 16 + m16;
      int k0 = kt * 32 + qd * 8;
      const float* src = (k0 < 128) ? (Wi + n * Ev + k0) : (Wh + n * Hv + (k0 - 128));
      f32x4 f0 = *(const f32x4*)(src);
      f32x4 f1 = *(const f32x4*)(src + 4);
      bf16x8 w;
      w[0] = (short)f2bf(f0[0]); w[1] = (short)f2bf(f0[1]);
      w[2] = (short)f2bf(f0[2]); w[3] = (short)f2bf(f0[3]);
      w[4] = (short)f2bf(f1[0]); w[5] = (short)f2bf(f1[1]);
      w[6] = (short)f2bf(f1[2]); w[7] = (short)f2bf(f1[3]);
      wf[kt][nt] = w;
    }
  }

  unsigned* hb_g = hbuf + (size_t)g * (2 * GM * Hv);
  unsigned* cntg = (unsigned*)((char*)cnt + g * 64);

#pragma unroll 1
  for (int s = 0; s < Sv; ++s) {
    const int p = s & 1;

    // ---- stage x part (k 0..127): gather embed rows, split hi/lo
    {
      int r  = tid >> 4;
      int k0 = (tid & 15) * 8;
      int tok = enc_in[(g * GM + r) * Sv + s];
      const float* xs = embed + tok * Ev + k0;
      f32x4 f0 = *(const f32x4*)xs;
      f32x4 f1 = *(const f32x4*)(xs + 4);
      bf16x8 xh, xl;
#pragma unroll
      for (int j = 0; j < 4; ++j) {
        unsigned short hi = f2bf(f0[j]);
        xh[j] = (short)hi; xl[j] = (short)f2bf(f0[j] - bf2f(hi));
      }
#pragma unroll
      for (int j = 0; j < 4; ++j) {
        unsigned short hi = f2bf(f1[j]);
        xh[4 + j] = (short)hi; xl[4 + j] = (short)f2bf(f1[j] - bf2f(hi));
      }
      *(bf16x8*)&Ahi[r][k0] = xh;
      *(bf16x8*)&Alo[r][k0] = xl;
    }
    // ---- stage h part (k 128..639) from packed global buffer (parity p)
    {
      const uint4* hsrc = (const uint4*)(hb_g + (size_t)p * (GM * Hv));
#pragma unroll
      for (int c = 0; c < 8; ++c) {
        uint4 v = hsrc[c * 256 + tid];
        int di  = (c * 256 + tid) * 4;
        int r   = di >> 9;
        int col = di & 511;
        short4v hi4, lo4;
        hi4[0] = (short)(v.x & 0xffff); lo4[0] = (short)(v.x >> 16);
        hi4[1] = (short)(v.y & 0xffff); lo4[1] = (short)(v.y >> 16);
        hi4[2] = (short)(v.z & 0xffff); lo4[2] = (short)(v.z >> 16);
        hi4[3] = (short)(v.w & 0xffff); lo4[3] = (short)(v.w >> 16);
        *(short4v*)&Ahi[r][128 + col] = hi4;
        *(short4v*)&Alo[r][128 + col] = lo4;
      }
    }
    __syncthreads();

    // ---- MFMA: z(:, wave-gate cols) = (A_hi + A_lo) @ W^T, fp32 accumulate
    f32x4 acc0 = {0.f, 0.f, 0.f, 0.f};
    f32x4 acc1 = {0.f, 0.f, 0.f, 0.f};
#pragma unroll
    for (int kt = 0; kt < KT; ++kt) {
      bf16x8 ah = *(const bf16x8*)&Ahi[m16][kt * 32 + qd * 8];
      bf16x8 al = *(const bf16x8*)&Alo[m16][kt * 32 + qd * 8];
      acc0 = __builtin_amdgcn_mfma_f32_16x16x32_bf16(ah, wf[kt][0], acc0, 0, 0, 0);
      acc0 = __builtin_amdgcn_mfma_f32_16x16x32_bf16(al, wf[kt][0], acc0, 0, 0, 0);
      acc1 = __builtin_amdgcn_mfma_f32_16x16x32_bf16(ah, wf[kt][1], acc1, 0, 0, 0);
      acc1 = __builtin_amdgcn_mfma_f32_16x16x32_bf16(al, wf[kt][1], acc1, 0, 0, 0);
    }
    // C/D layout: col = lane&15, row = (lane>>4)*4 + reg
    {
      int row = qd * 4;
#pragma unroll
      for (int rr = 0; rr < 4; ++rr) {
        zbuf[wave][row + rr][m16]      = acc0[rr];
        zbuf[wave][row + rr][16 + m16] = acc1[rr];
      }
    }
    __syncthreads();

    // ---- gates/state for this wg's 16x32 h-slice; write packed h + enc_out
#pragma unroll
    for (int half_ = 0; half_ < 2; ++half_) {
      int e = tid + half_ * 256;
      int r = e >> 5, j = e & 31;
      float iz = zbuf[0][r][j] + biasLDS[j];
      float fz = zbuf[1][r][j] + biasLDS[32 + j];
      float gz = zbuf[2][r][j] + biasLDS[64 + j];
      float oz = zbuf[3][r][j] + biasLDS[96 + j];
      float cn = sigm(fz) * cbuf[r][j] + sigm(iz) * tanh_fast(gz);
      float hn = sigm(oz) * tanh_fast(cn);
      cbuf[r][j] = cn;
      unsigned short hh = f2bf(hn);
      unsigned short hl = f2bf(hn - bf2f(hh));
      unsigned pk = (unsigned)hh | ((unsigned)hl << 16);
      __hip_atomic_store(hb_g + (size_t)(p ^ 1) * (GM * Hv) + r * Hv + cb * 32 + j,
                         pk, __ATOMIC_RELAXED, __HIP_MEMORY_SCOPE_AGENT);
      enc_out[((size_t)(g * GM + r) * Sv + s) * Hv + cb * 32 + j] = __float2half(hn);
    }

    // ---- one barrier per step among the 16 wgs of this group.
    // __syncthreads drains vmcnt(0), so all threads' stores are complete here.
    __syncthreads();
    if (tid == 0) {
      __threadfence();                 // release
      atomicAdd(cntg, 1u);
      unsigned target = (unsigned)(WPG * (s + 1));
      while (__hip_atomic_load(cntg, __ATOMIC_RELAXED, __HIP_MEMORY_SCOPE_AGENT) < target) {
        __builtin_amdgcn_s_sleep(2);
      }
      __threadfence();                 // acquire
    }
    __syncthreads();
  }
}

// One wg per batch row: scores = enc_out[b] @ We, softmax over S, ctx, then
// pa/pt dots, tiled over T=32 into d_out. All fp32 except enc_out fp16 reads.
__global__ __launch_bounds__(256)
void attn_out(const __half* __restrict__ enc_out, const float* __restrict__ Wf,
              const float* __restrict__ Wa, const float* __restrict__ ba,
              const float* __restrict__ Wt, const float* __restrict__ bt,
              float* __restrict__ out)
{
  __shared__ float We[512];
  __shared__ float sc[256];
  __shared__ float ctx[512];
  __shared__ float red[8];
  const int tid = threadIdx.x;
  const int b   = blockIdx.x;
  const int wv  = tid >> 6;
  const int ln  = tid & 63;

  We[tid] = Wf[tid];
  We[tid + 256] = Wf[tid + 256];
  __syncthreads();

  // score for s = tid (per-thread row; L1 catches the 64B-line reuse)
  const __half2* r2 = (const __half2*)(enc_out + ((size_t)b * Sv + tid) * Hv);
  float a = 0.f;
#pragma unroll 4
  for (int k2 = 0; k2 < Hv / 2; ++k2) {
    float2 f = __half22float2(r2[k2]);
    a += f.x * We[2 * k2] + f.y * We[2 * k2 + 1];
  }

  // softmax over S=256
  float m = a;
  for (int off = 32; off; off >>= 1) m = fmaxf(m, __shfl_down(m, off));
  if (ln == 0) red[wv] = m;
  __syncthreads();
  if (tid == 0) red[4] = fmaxf(fmaxf(red[0], red[1]), fmaxf(red[2], red[3]));
  __syncthreads();
  float e = __expf(a - red[4]);
  float ssum = e;
  for (int off = 32; off; off >>= 1) ssum += __shfl_down(ssum, off);
  if (ln == 0) red[wv] = ssum;
  __syncthreads();
  if (tid == 0) red[5] = red[0] + red[1] + red[2] + red[3];
  __syncthreads();
  sc[tid] = e * (1.f / red[5]);
  __syncthreads();

  // ctx[h] = sum_s w[s] * enc_out[b][s][h]; thread owns cols 2*tid, 2*tid+1
  {
    float a0 = 0.f, a1 = 0.f;
    const __half2* base = (const __half2*)(enc_out + (size_t)b * Sv * Hv) + tid;
#pragma unroll 4
    for (int s2 = 0; s2 < Sv; ++s2) {
      float2 f = __half22float2(base[s2 * (Hv / 2)]);
      float w = sc[s2];
      a0 += w * f.x;
      a1 += w * f.y;
    }
    ctx[2 * tid] = a0;
    ctx[2 * tid + 1] = a1;
  }
  __syncthreads();

  // pa (8) and pt (80) dots; outputs constant over T -> tile
  if (tid < 88) {
    const float* wr = (tid < 8) ? (Wa + tid * Hv) : (Wt + (tid - 8) * Hv);
    float o = (tid < 8) ? ba[tid] : bt[tid - 8];
    for (int k = 0; k < Hv; ++k) o += ctx[k] * wr[k];
    if (tid < 8) {
      float* o0 = out + (size_t)b * Tv * 8;
#pragma unroll
      for (int t = 0; t < Tv; ++t) o0[t * 8 + tid] = o;
    } else {
      int n = tid - 8;
      float* o1 = out + 65536 + (size_t)b * Tv * 80;
#pragma unroll
      for (int t = 0; t < Tv; ++t) o1[t * 80 + n] = o;
    }
  }
}

extern "C" void kernel_launch(void* const* d_in, const int* in_sizes, int n_in,
                              void* d_out, int out_size, void* d_ws, size_t ws_size,
                              hipStream_t stream)
{
  (void)in_sizes; (void)n_in; (void)out_size; (void)ws_size;
  const int*   enc_in = (const int*)d_in[0];
  const float* embed  = (const float*)d_in[2];
  const float* Wi     = (const float*)d_in[3];
  const float* Wh     = (const float*)d_in[4];
  const float* be     = (const float*)d_in[5];
  const float* Wa     = (const float*)d_in[11];
  const float* ba     = (const float*)d_in[12];
  const float* Wt     = (const float*)d_in[13];
  const float* bt     = (const float*)d_in[14];
  const float* Wf     = (const float*)d_in[15];
  // d_in[1] decoder_target, [6..10] decoder weights, [16] bf: dead code (softmax shift-invariance)

  char* ws = (char*)d_ws;
  unsigned* cnt    = (unsigned*)ws;                        // 16 counters @64B stride = 1KB
  unsigned* hbuf   = (unsigned*)(ws + 1024);               // 16 groups x 2 parities x 16x512 packed = 1MB
  __half*   encout = (__half*)(ws + 1024 + (1u << 20));    // 256x256x512 fp16 = 64MB

  hipMemsetAsync(d_ws, 0, 1024 + (1u << 20), stream);      // zero h0 + barrier counters

  lstm_enc<<<dim3(256), dim3(256), 0, stream>>>(enc_in, embed, Wi, Wh, be, cnt, hbuf, encout);
  attn_out<<<dim3(256), dim3(256), 0, stream>>>(encout, Wf, Wa, ba, Wt, bt, (float*)d_out);
}

// Round 2
// 1837.112 us; speedup vs baseline: 1.8660x; 1.8660x over previous
//
#include <hip/hip_runtime.h>
#include <hip/hip_fp16.h>

// Problem: B=256,S=256,T=32,H=512,E=128,V=1000,A=8,NT=80.
// Key math fact: scores = enc_score + h@Wd + bf adds a per-column constant over
// the softmax axis (S) -> softmax weights are decoder-independent -> the whole
// decoder is dead code; outputs are pa/pt tiled over T.
//
// Remaining work: 256 sequential LSTM steps (M=256,N=2048,K=640 GEMM each) +
// one attention readout. Structure: persistent kernel, 16 batch-groups x
// (16 rows, 16 wgs), weights in registers (bf16), activations split hi/lo bf16
// (2 MFMAs, ~fp32-accurate), per-group atomic barrier once per step.
//
// R1 lesson: per-step __threadfence() emitted buffer_wbl2 + buffer_inv ->
// whole-L2 writeback+invalidate every step -> 100 MB of embed re-fetch and
// 13 us/step. Fix: no fences at all. h exchange uses agent-scope atomic
// stores (write-through coherent) + agent-scope atomic loads (bypass stale
// L1/L2 per-instruction). __syncthreads() drains vmcnt(0), which completes
// the coherent stores before the barrier fetch_add.

#define Bv 256
#define Sv 256
#define Tv 32
#define Hv 512
#define Ev 128
#define KT 20          // k-tiles of 32 over K=640 (4 x-tiles + 16 h-tiles)
#define LDSA 648       // padded k-stride for LDS A planes (shorts)
#define GM 16          // batch rows per group
#define WPG 16         // workgroups per group

typedef __attribute__((ext_vector_type(8))) short bf16x8;
typedef __attribute__((ext_vector_type(4))) float f32x4;

__device__ __forceinline__ unsigned short f2bf(float x) {   // RNE fp32->bf16
  unsigned u = __builtin_bit_cast(unsigned, x);
  u += 0x7fffu + ((u >> 16) & 1u);
  return (unsigned short)(u >> 16);
}
__device__ __forceinline__ float bf2f(unsigned short h) {
  unsigned u = ((unsigned)h) << 16;
  return __builtin_bit_cast(float, u);
}
__device__ __forceinline__ float sigm(float x) { return 1.0f / (1.0f + __expf(-x)); }
__device__ __forceinline__ float tanh_fast(float x) {
  x = fminf(15.f, fmaxf(-15.f, x));
  float e = __expf(2.f * x);
  return (e - 1.f) / (e + 1.f);
}

// hbuf layout: per group g, parity p: [16 rows][512 cols] of packed (bf16_hi | bf16_lo<<16)
// cnt: one counter per group at 64B stride (avoid same-cacheline contention).
__global__ __launch_bounds__(256, 2)
void lstm_enc(const int* __restrict__ enc_in, const float* __restrict__ embed,
              const float* __restrict__ Wi, const float* __restrict__ Wh,
              const float* __restrict__ be,
              unsigned* __restrict__ cnt, unsigned* __restrict__ hbuf,
              __half* __restrict__ enc_out)
{
  __shared__ __attribute__((aligned(16))) short Ahi[GM][LDSA];
  __shared__ __attribute__((aligned(16))) short Alo[GM][LDSA];
  __shared__ float zbuf[4][GM][36];
  __shared__ float cbuf[GM][32];
  __shared__ float biasLDS[128];

  const int tid  = threadIdx.x;
  const int wg   = blockIdx.x;
  const int g    = wg & 15;   // group; members share blockIdx%8 -> same XCD (perf heuristic only)
  const int cb   = wg >> 4;   // column block: owns j in [cb*32, cb*32+32)
  const int wave = tid >> 6;  // wave == gate q (0=i,1=f,2=g,3=o)
  const int lane = tid & 63;
  const int m16  = lane & 15;
  const int qd   = lane >> 4;

  if (tid < 128) biasLDS[tid] = be[(tid >> 5) * 512 + cb * 32 + (tid & 31)];
  cbuf[tid >> 5][tid & 31] = 0.f;
  { int e2 = tid + 256; cbuf[e2 >> 5][e2 & 31] = 0.f; }

  // ---- W fragments in registers: B-operand layout B[k][n]: lane holds
  // W'[n = base + (lane&15)][k = kt*32 + (lane>>4)*8 + j], j=0..7, single bf16.
  bf16x8 wf[KT][2];
#pragma unroll
  for (int kt = 0; kt < KT; ++kt) {
#pragma unroll
    for (int nt = 0; nt < 2; ++nt) {
      int n  = wave * 512 + cb * 32 + nt * 16 + m16;
      int k0 = kt * 32 + qd * 8;
      const float* src = (k0 < 128) ? (Wi + n * Ev + k0) : (Wh + n * Hv + (k0 - 128));
      f32x4 f0 = *(const f32x4*)(src);
      f32x4 f1 = *(const f32x4*)(src + 4);
      bf16x8 w;
      w[0] = (short)f2bf(f0[0]); w[1] = (short)f2bf(f0[1]);
      w[2] = (short)f2bf(f0[2]); w[3] = (short)f2bf(f0[3]);
      w[4] = (short)f2bf(f1[0]); w[5] = (short)f2bf(f1[1]);
      w[6] = (short)f2bf(f1[2]); w[7] = (short)f2bf(f1[3]);
      wf[kt][nt] = w;
    }
  }

  unsigned* hb_g = hbuf + (size_t)g * (2 * GM * Hv);
  unsigned* cntg = (unsigned*)((char*)cnt + g * 64);

#pragma unroll 1
  for (int s = 0; s < Sv; ++s) {
    const int p = s & 1;

    // ---- stage x part (k 0..127): gather embed rows, split hi/lo
    {
      int r  = tid >> 4;
      int k0 = (tid & 15) * 8;
      int tok = enc_in[(g * GM + r) * Sv + s];
      const float* xs = embed + tok * Ev + k0;
      f32x4 f0 = *(const f32x4*)xs;
      f32x4 f1 = *(const f32x4*)(xs + 4);
      bf16x8 xh, xl;
#pragma unroll
      for (int j = 0; j < 4; ++j) {
        unsigned short hi = f2bf(f0[j]);
        xh[j] = (short)hi; xl[j] = (short)f2bf(f0[j] - bf2f(hi));
      }
#pragma unroll
      for (int j = 0; j < 4; ++j) {
        unsigned short hi = f2bf(f1[j]);
        xh[4 + j] = (short)hi; xl[4 + j] = (short)f2bf(f1[j] - bf2f(hi));
      }
      *(bf16x8*)&Ahi[r][k0] = xh;
      *(bf16x8*)&Alo[r][k0] = xl;
    }
    // ---- stage h part (k 128..639): coherent agent-scope 8B loads of the
    // packed buffer (no cache-nuking fence needed; these bypass stale L1/L2).
    {
      const unsigned long long* hsrc =
          (const unsigned long long*)(hb_g + (size_t)p * (GM * Hv));
#pragma unroll
      for (int c = 0; c < 16; ++c) {
        unsigned long long v = __hip_atomic_load(hsrc + c * 256 + tid,
                                                 __ATOMIC_RELAXED, __HIP_MEMORY_SCOPE_AGENT);
        unsigned w0 = (unsigned)v, w1 = (unsigned)(v >> 32);
        // word index wi = (c*256+tid)*2 -> r = c, col = 2*tid
        int col = 2 * tid;
        unsigned hi2 = (w0 & 0xffffu) | (w1 << 16);
        unsigned lo2 = (w0 >> 16) | (w1 & 0xffff0000u);
        *(unsigned*)&Ahi[c][128 + col] = hi2;
        *(unsigned*)&Alo[c][128 + col] = lo2;
      }
    }
    __syncthreads();

    // ---- MFMA: z(:, wave-gate cols) = (A_hi + A_lo) @ W^T, fp32 accumulate
    f32x4 acc0 = {0.f, 0.f, 0.f, 0.f};
    f32x4 acc1 = {0.f, 0.f, 0.f, 0.f};
#pragma unroll
    for (int kt = 0; kt < KT; ++kt) {
      bf16x8 ah = *(const bf16x8*)&Ahi[m16][kt * 32 + qd * 8];
      bf16x8 al = *(const bf16x8*)&Alo[m16][kt * 32 + qd * 8];
      acc0 = __builtin_amdgcn_mfma_f32_16x16x32_bf16(ah, wf[kt][0], acc0, 0, 0, 0);
      acc0 = __builtin_amdgcn_mfma_f32_16x16x32_bf16(al, wf[kt][0], acc0, 0, 0, 0);
      acc1 = __builtin_amdgcn_mfma_f32_16x16x32_bf16(ah, wf[kt][1], acc1, 0, 0, 0);
      acc1 = __builtin_amdgcn_mfma_f32_16x16x32_bf16(al, wf[kt][1], acc1, 0, 0, 0);
    }
    // C/D layout: col = lane&15, row = (lane>>4)*4 + reg
    {
      int row = qd * 4;
#pragma unroll
      for (int rr = 0; rr < 4; ++rr) {
        zbuf[wave][row + rr][m16]      = acc0[rr];
        zbuf[wave][row + rr][16 + m16] = acc1[rr];
      }
    }
    __syncthreads();

    // ---- gates/state for this wg's 16x32 h-slice; write packed h + enc_out
#pragma unroll
    for (int half_ = 0; half_ < 2; ++half_) {
      int e = tid + half_ * 256;
      int r = e >> 5, j = e & 31;
      float iz = zbuf[0][r][j] + biasLDS[j];
      float fz = zbuf[1][r][j] + biasLDS[32 + j];
      float gz = zbuf[2][r][j] + biasLDS[64 + j];
      float oz = zbuf[3][r][j] + biasLDS[96 + j];
      float cn = sigm(fz) * cbuf[r][j] + sigm(iz) * tanh_fast(gz);
      float hn = sigm(oz) * tanh_fast(cn);
      cbuf[r][j] = cn;
      unsigned short hh = f2bf(hn);
      unsigned short hl = f2bf(hn - bf2f(hh));
      unsigned pk = (unsigned)hh | ((unsigned)hl << 16);
      __hip_atomic_store(hb_g + (size_t)(p ^ 1) * (GM * Hv) + r * Hv + cb * 32 + j,
                         pk, __ATOMIC_RELAXED, __HIP_MEMORY_SCOPE_AGENT);
      enc_out[((size_t)(g * GM + r) * Sv + s) * Hv + cb * 32 + j] = __float2half(hn);
    }

    // ---- one fence-free barrier per step among the 16 wgs of this group.
    // __syncthreads drains vmcnt(0) in every wave -> all coherent h stores
    // are complete at the coherence point before tid0 signals arrival.
    __syncthreads();
    if (tid == 0) {
      __hip_atomic_fetch_add(cntg, 1u, __ATOMIC_RELAXED, __HIP_MEMORY_SCOPE_AGENT);
      const unsigned target = (unsigned)(WPG * (s + 1));
      while (__hip_atomic_load(cntg, __ATOMIC_RELAXED, __HIP_MEMORY_SCOPE_AGENT) < target) {
        __builtin_amdgcn_s_sleep(1);
      }
    }
    __syncthreads();
  }
}

// One wg per batch row: scores = enc_out[b] @ We, softmax over S, ctx, then
// pa/pt dots, tiled over T=32 into d_out. All fp32 except enc_out fp16 reads.
__global__ __launch_bounds__(256)
void attn_out(const __half* __restrict__ enc_out, const float* __restrict__ Wf,
              const float* __restrict__ Wa, const float* __restrict__ ba,
              const float* __restrict__ Wt, const float* __restrict__ bt,
              float* __restrict__ out)
{
  __shared__ float We[512];
  __shared__ float sc[256];
  __shared__ float ctx[512];
  __shared__ float red[8];
  const int tid = threadIdx.x;
  const int b   = blockIdx.x;
  const int wv  = tid >> 6;
  const int ln  = tid & 63;

  We[tid] = Wf[tid];
  We[tid + 256] = Wf[tid + 256];
  __syncthreads();

  // score for s = tid (per-thread row; L1 catches the 64B-line reuse)
  const __half2* r2 = (const __half2*)(enc_out + ((size_t)b * Sv + tid) * Hv);
  float a = 0.f;
#pragma unroll 4
  for (int k2 = 0; k2 < Hv / 2; ++k2) {
    float2 f = __half22float2(r2[k2]);
    a += f.x * We[2 * k2] + f.y * We[2 * k2 + 1];
  }

  // softmax over S=256
  float m = a;
  for (int off = 32; off; off >>= 1) m = fmaxf(m, __shfl_down(m, off));
  if (ln == 0) red[wv] = m;
  __syncthreads();
  if (tid == 0) red[4] = fmaxf(fmaxf(red[0], red[1]), fmaxf(red[2], red[3]));
  __syncthreads();
  float e = __expf(a - red[4]);
  float ssum = e;
  for (int off = 32; off; off >>= 1) ssum += __shfl_down(ssum, off);
  if (ln == 0) red[wv] = ssum;
  __syncthreads();
  if (tid == 0) red[5] = red[0] + red[1] + red[2] + red[3];
  __syncthreads();
  sc[tid] = e * (1.f / red[5]);
  __syncthreads();

  // ctx[h] = sum_s w[s] * enc_out[b][s][h]; thread owns cols 2*tid, 2*tid+1
  {
    float a0 = 0.f, a1 = 0.f;
    const __half2* base = (const __half2*)(enc_out + (size_t)b * Sv * Hv) + tid;
#pragma unroll 4
    for (int s2 = 0; s2 < Sv; ++s2) {
      float2 f = __half22float2(base[s2 * (Hv / 2)]);
      float w = sc[s2];
      a0 += w * f.x;
      a1 += w * f.y;
    }
    ctx[2 * tid] = a0;
    ctx[2 * tid + 1] = a1;
  }
  __syncthreads();

  // pa (8) and pt (80) dots; outputs constant over T -> tile
  if (tid < 88) {
    const float* wr = (tid < 8) ? (Wa + tid * Hv) : (Wt + (tid - 8) * Hv);
    float o = (tid < 8) ? ba[tid] : bt[tid - 8];
    for (int k = 0; k < Hv; ++k) o += ctx[k] * wr[k];
    if (tid < 8) {
      float* o0 = out + (size_t)b * Tv * 8;
#pragma unroll
      for (int t = 0; t < Tv; ++t) o0[t * 8 + tid] = o;
    } else {
      int n = tid - 8;
      float* o1 = out + 65536 + (size_t)b * Tv * 80;
#pragma unroll
      for (int t = 0; t < Tv; ++t) o1[t * 80 + n] = o;
    }
  }
}

extern "C" void kernel_launch(void* const* d_in, const int* in_sizes, int n_in,
                              void* d_out, int out_size, void* d_ws, size_t ws_size,
                              hipStream_t stream)
{
  (void)in_sizes; (void)n_in; (void)out_size; (void)ws_size;
  const int*   enc_in = (const int*)d_in[0];
  const float* embed  = (const float*)d_in[2];
  const float* Wi     = (const float*)d_in[3];
  const float* Wh     = (const float*)d_in[4];
  const float* be     = (const float*)d_in[5];
  const float* Wa     = (const float*)d_in[11];
  const float* ba     = (const float*)d_in[12];
  const float* Wt     = (const float*)d_in[13];
  const float* bt     = (const float*)d_in[14];
  const float* Wf     = (const float*)d_in[15];
  // d_in[1] decoder_target, [6..10] decoder weights, [16] bf: dead code (softmax shift-invariance)

  char* ws = (char*)d_ws;
  unsigned* cnt    = (unsigned*)ws;                        // 16 counters @64B stride = 1KB
  unsigned* hbuf   = (unsigned*)(ws + 1024);               // 16 groups x 2 parities x 16x512 packed = 1MB
  __half*   encout = (__half*)(ws + 1024 + (1u << 20));    // 256x256x512 fp16 = 64MB

  hipMemsetAsync(d_ws, 0, 1024 + (1u << 20), stream);      // zero h0 + barrier counters

  lstm_enc<<<dim3(256), dim3(256), 0, stream>>>(enc_in, embed, Wi, Wh, be, cnt, hbuf, encout);
  attn_out<<<dim3(256), dim3(256), 0, stream>>>(encout, Wf, Wa, ba, Wt, bt, (float*)d_out);
}